// Round 2
// baseline (285.299 us; speedup 1.0000x reference)
//
#include <hip/hip_runtime.h>

// SmoothL1 word loss (packed mean) + sentence loss (per-batch time-means).
// preds/targets: [B=32, T=2048, D=512] fp32; decode_lengths: [32] int32; out: 1 fp32.
// BETA = 1.0  -> smooth_l1(d) = |d|<1 ? 0.5 d^2 : |d| - 0.5
//
// Structure: atomic-free 3-pass hierarchical reduction.
//   pass1: per-(b,chunk) partial column sums + word-loss partial  -> ws (no init needed)
//   pass2: per-b fold over valid chunks -> sentb[b], wordb[b]
//   pass3: single wave combines 32 per-b values -> scalar out

#define BATCH 32
#define TLEN  2048
#define DDIM  512
#define CHUNK 16
#define NCH   (TLEN / CHUNK)      // 128 chunks per batch
#define P1_THREADS 128            // 128 threads x float4 = 512 columns

__device__ __forceinline__ float sl1(float d) {
    float ad = fabsf(d);
    return ad < 1.0f ? 0.5f * d * d : ad - 0.5f;
}

// ---------------- Pass 1: per-chunk partials (no atomics) ----------------
__global__ __launch_bounds__(P1_THREADS)
void pass1(const float* __restrict__ preds, const float* __restrict__ targs,
           const int* __restrict__ lens,
           float4* __restrict__ colp_part,   // [B*NCH][D/4]
           float4* __restrict__ colt_part,   // [B*NCH][D/4]
           float* __restrict__ wpart)        // [B*NCH]
{
    const int b   = blockIdx.x;
    const int c   = blockIdx.y;
    const int len = lens[b];
    const int t0  = c * CHUNK;
    if (t0 >= len) return;                    // masked-out chunk: zero reads, zero writes
    const int t1  = min(t0 + CHUNK, len);

    const float4* __restrict__ p4 = (const float4*)(preds + (size_t)b * TLEN * DDIM);
    const float4* __restrict__ q4 = (const float4*)(targs + (size_t)b * TLEN * DDIM);
    const int lane4 = threadIdx.x;            // float4 column index

    float4 sp = make_float4(0.f, 0.f, 0.f, 0.f);
    float4 st = make_float4(0.f, 0.f, 0.f, 0.f);
    float  w  = 0.f;

    if (t1 - t0 == CHUNK) {                   // full chunk: unrolled, many loads in flight
        #pragma unroll
        for (int i = 0; i < CHUNK; ++i) {
            const size_t r = (size_t)(t0 + i) * (DDIM / 4) + lane4;
            float4 p = p4[r];
            float4 q = q4[r];
            sp.x += p.x; sp.y += p.y; sp.z += p.z; sp.w += p.w;
            st.x += q.x; st.y += q.y; st.z += q.z; st.w += q.w;
            w += sl1(p.x - q.x) + sl1(p.y - q.y) + sl1(p.z - q.z) + sl1(p.w - q.w);
        }
    } else {                                  // tail chunk (at most one per batch)
        for (int t = t0; t < t1; ++t) {
            const size_t r = (size_t)t * (DDIM / 4) + lane4;
            float4 p = p4[r];
            float4 q = q4[r];
            sp.x += p.x; sp.y += p.y; sp.z += p.z; sp.w += p.w;
            st.x += q.x; st.y += q.y; st.z += q.z; st.w += q.w;
            w += sl1(p.x - q.x) + sl1(p.y - q.y) + sl1(p.z - q.z) + sl1(p.w - q.w);
        }
    }

    const size_t slot = (size_t)(b * NCH + c) * (DDIM / 4) + lane4;
    colp_part[slot] = sp;                     // plain coalesced float4 stores
    colt_part[slot] = st;

    // word partial: wave reduce (wave=64) then tiny LDS fold, one store per block
    #pragma unroll
    for (int off = 32; off; off >>= 1) w += __shfl_down(w, off);
    __shared__ float ws[P1_THREADS / 64];
    if ((threadIdx.x & 63) == 0) ws[threadIdx.x >> 6] = w;
    __syncthreads();
    if (threadIdx.x == 0) {
        float tot = 0.f;
        #pragma unroll
        for (int i = 0; i < P1_THREADS / 64; ++i) tot += ws[i];
        wpart[b * NCH + c] = tot;
    }
}

// ---------------- Pass 2: per-b fold over valid chunks ----------------
__global__ __launch_bounds__(P1_THREADS)
void pass2(const float4* __restrict__ colp_part, const float4* __restrict__ colt_part,
           const float* __restrict__ wpart, const int* __restrict__ lens,
           float* __restrict__ sentb,        // [B]  sum_d sl1(mean diff)
           float* __restrict__ wordb)        // [B]  sum of word partials
{
    const int b   = blockIdx.x;
    const int len = lens[b];
    const int nch = (len + CHUNK - 1) / CHUNK;   // only these chunks were written
    const int t   = threadIdx.x;                 // owns one float4 column group

    float4 sp = make_float4(0.f, 0.f, 0.f, 0.f);
    float4 st = make_float4(0.f, 0.f, 0.f, 0.f);
    for (int c = 0; c < nch; ++c) {
        const size_t slot = (size_t)(b * NCH + c) * (DDIM / 4) + t;
        float4 p = colp_part[slot];
        float4 q = colt_part[slot];
        sp.x += p.x; sp.y += p.y; sp.z += p.z; sp.w += p.w;
        st.x += q.x; st.y += q.y; st.z += q.z; st.w += q.w;
    }
    const float invL = 1.0f / (float)len;
    float s = sl1((sp.x - st.x) * invL) + sl1((sp.y - st.y) * invL)
            + sl1((sp.z - st.z) * invL) + sl1((sp.w - st.w) * invL);

    float wsum = 0.f;
    for (int c = t; c < nch; c += P1_THREADS) wsum += wpart[b * NCH + c];

    #pragma unroll
    for (int off = 32; off; off >>= 1) {
        s    += __shfl_down(s, off);
        wsum += __shfl_down(wsum, off);
    }
    __shared__ float rs[P1_THREADS / 64], rw[P1_THREADS / 64];
    if ((t & 63) == 0) { rs[t >> 6] = s; rw[t >> 6] = wsum; }
    __syncthreads();
    if (t == 0) {
        float st_ = 0.f, wt_ = 0.f;
        #pragma unroll
        for (int i = 0; i < P1_THREADS / 64; ++i) { st_ += rs[i]; wt_ += rw[i]; }
        sentb[b] = st_;
        wordb[b] = wt_;
    }
}

// ---------------- Pass 3: combine 32 per-b values -> scalar ----------------
__global__ __launch_bounds__(64)
void pass3(const float* __restrict__ sentb, const float* __restrict__ wordb,
           const int* __restrict__ lens, float* __restrict__ out)
{
    const int t = threadIdx.x;
    float s = 0.f, w = 0.f, L = 0.f;
    if (t < BATCH) { s = sentb[t]; w = wordb[t]; L = (float)lens[t]; }
    #pragma unroll
    for (int off = 32; off; off >>= 1) {
        s += __shfl_down(s, off);
        w += __shfl_down(w, off);
        L += __shfl_down(L, off);
    }
    if (t == 0) {
        const float word_loss = w / (L * (float)DDIM);
        const float sent_loss = s / ((float)DDIM * (float)BATCH);
        out[0] = word_loss + sent_loss;
    }
}

extern "C" void kernel_launch(void* const* d_in, const int* in_sizes, int n_in,
                              void* d_out, int out_size, void* d_ws, size_t ws_size,
                              hipStream_t stream) {
    const float* preds = (const float*)d_in[0];
    const float* targs = (const float*)d_in[1];
    const int*   lens  = (const int*)d_in[2];
    float* out = (float*)d_out;

    // Workspace (fp32, no init required — consumers only read slots producers wrote):
    //   colp_part [B*NCH*D] = 8 MB, colt_part = 8 MB, wpart [B*NCH], sentb[B], wordb[B]
    float* colp = (float*)d_ws;
    float* colt = colp + (size_t)BATCH * NCH * DDIM;
    float* wpart = colt + (size_t)BATCH * NCH * DDIM;
    float* sentb = wpart + BATCH * NCH;
    float* wordb = sentb + BATCH;

    dim3 grid1(BATCH, NCH);
    pass1<<<grid1, P1_THREADS, 0, stream>>>(preds, targs, lens,
                                            (float4*)colp, (float4*)colt, wpart);
    pass2<<<BATCH, P1_THREADS, 0, stream>>>((const float4*)colp, (const float4*)colt,
                                            wpart, lens, sentb, wordb);
    pass3<<<1, 64, 0, stream>>>(sentb, wordb, lens, out);
}

// Round 3
// 274.092 us; speedup vs baseline: 1.0409x; 1.0409x over previous
//
#include <hip/hip_runtime.h>

// SmoothL1 word loss (packed mean) + sentence loss (per-batch time-means).
// preds/targets: [B=32, T=2048, D=512] fp32; decode_lengths: [32] int32; out: 1 fp32.
// BETA = 1.0  -> smooth_l1(d) = |d|<1 ? 0.5 d^2 : |d| - 0.5
//
// Atomic-free 3-pass hierarchical reduction. R3: CHUNK 32 (256-thread blocks,
// two row-halves folded through LDS) halves partial traffic vs R2.

#define BATCH 32
#define TLEN  2048
#define DDIM  512
#define CHUNK 32
#define NCH   (TLEN / CHUNK)      // 64 chunks per batch
#define P1_THREADS 256            // 2 row-halves x 128 col-threads (float4)

__device__ __forceinline__ float sl1(float d) {
    float ad = fabsf(d);
    return ad < 1.0f ? 0.5f * d * d : ad - 0.5f;
}

// ---------------- Pass 1: per-chunk partials (no atomics) ----------------
__global__ __launch_bounds__(P1_THREADS)
void pass1(const float* __restrict__ preds, const float* __restrict__ targs,
           const int* __restrict__ lens,
           float4* __restrict__ colp_part,   // [B*NCH][D/4]
           float4* __restrict__ colt_part,   // [B*NCH][D/4]
           float* __restrict__ wpart)        // [B*NCH]
{
    const int b   = blockIdx.x;
    const int c   = blockIdx.y;
    const int len = lens[b];
    const int t0  = c * CHUNK;
    if (t0 >= len) return;                    // masked-out chunk: zero reads/writes
    const int t1  = min(t0 + CHUNK, len);

    const int half  = threadIdx.x >> 7;       // 0: rows t0..t0+15, 1: t0+16..t0+31
    const int lane4 = threadIdx.x & 127;      // float4 column index
    const int r0    = t0 + half * 16;
    const int r1    = min(r0 + 16, t1);

    const float4* __restrict__ p4 = (const float4*)(preds + (size_t)b * TLEN * DDIM);
    const float4* __restrict__ q4 = (const float4*)(targs + (size_t)b * TLEN * DDIM);

    float4 sp = make_float4(0.f, 0.f, 0.f, 0.f);
    float4 st = make_float4(0.f, 0.f, 0.f, 0.f);
    float  w  = 0.f;

    if (r1 - r0 == 16) {                      // full half: 32 loads in flight
        #pragma unroll
        for (int i = 0; i < 16; ++i) {
            const size_t r = (size_t)(r0 + i) * (DDIM / 4) + lane4;
            float4 p = p4[r];
            float4 q = q4[r];
            sp.x += p.x; sp.y += p.y; sp.z += p.z; sp.w += p.w;
            st.x += q.x; st.y += q.y; st.z += q.z; st.w += q.w;
            w += sl1(p.x - q.x) + sl1(p.y - q.y) + sl1(p.z - q.z) + sl1(p.w - q.w);
        }
    } else {                                  // tail (possibly empty for half=1)
        for (int t = r0; t < r1; ++t) {
            const size_t r = (size_t)t * (DDIM / 4) + lane4;
            float4 p = p4[r];
            float4 q = q4[r];
            sp.x += p.x; sp.y += p.y; sp.z += p.z; sp.w += p.w;
            st.x += q.x; st.y += q.y; st.z += q.z; st.w += q.w;
            w += sl1(p.x - q.x) + sl1(p.y - q.y) + sl1(p.z - q.z) + sl1(p.w - q.w);
        }
    }

    // Fold half 1 into half 0 through LDS (4 KB, b128 access, conflict-free).
    __shared__ float4 lsp[128], lst[128];
    if (half == 1) { lsp[lane4] = sp; lst[lane4] = st; }
    __syncthreads();
    if (half == 0) {
        float4 o = lsp[lane4], u = lst[lane4];
        sp.x += o.x; sp.y += o.y; sp.z += o.z; sp.w += o.w;
        st.x += u.x; st.y += u.y; st.z += u.z; st.w += u.w;
        const size_t slot = (size_t)(b * NCH + c) * (DDIM / 4) + lane4;
        colp_part[slot] = sp;                 // coalesced float4 stores
        colt_part[slot] = st;
    }

    // Word partial: wave reduce (wave=64) then 4-wave LDS fold, one store/block.
    #pragma unroll
    for (int off = 32; off; off >>= 1) w += __shfl_down(w, off);
    __shared__ float ws[P1_THREADS / 64];
    if ((threadIdx.x & 63) == 0) ws[threadIdx.x >> 6] = w;
    __syncthreads();
    if (threadIdx.x == 0) {
        float tot = 0.f;
        #pragma unroll
        for (int i = 0; i < P1_THREADS / 64; ++i) tot += ws[i];
        wpart[b * NCH + c] = tot;
    }
}

// ---------------- Pass 2: per-b fold over valid chunks ----------------
__global__ __launch_bounds__(128)
void pass2(const float4* __restrict__ colp_part, const float4* __restrict__ colt_part,
           const float* __restrict__ wpart, const int* __restrict__ lens,
           float* __restrict__ sentb,        // [B]  sum_d sl1(mean diff)
           float* __restrict__ wordb)        // [B]  sum of word partials
{
    const int b   = blockIdx.x;
    const int len = lens[b];
    const int nch = (len + CHUNK - 1) / CHUNK;   // only these chunks were written
    const int t   = threadIdx.x;                 // owns one float4 column group

    float4 sp = make_float4(0.f, 0.f, 0.f, 0.f);
    float4 st = make_float4(0.f, 0.f, 0.f, 0.f);
    for (int c = 0; c < nch; ++c) {
        const size_t slot = (size_t)(b * NCH + c) * (DDIM / 4) + t;
        float4 p = colp_part[slot];
        float4 q = colt_part[slot];
        sp.x += p.x; sp.y += p.y; sp.z += p.z; sp.w += p.w;
        st.x += q.x; st.y += q.y; st.z += q.z; st.w += q.w;
    }
    const float invL = 1.0f / (float)len;
    float s = sl1((sp.x - st.x) * invL) + sl1((sp.y - st.y) * invL)
            + sl1((sp.z - st.z) * invL) + sl1((sp.w - st.w) * invL);

    float wsum = 0.f;
    for (int c = t; c < nch; c += 128) wsum += wpart[b * NCH + c];

    #pragma unroll
    for (int off = 32; off; off >>= 1) {
        s    += __shfl_down(s, off);
        wsum += __shfl_down(wsum, off);
    }
    __shared__ float rs[2], rw[2];
    if ((t & 63) == 0) { rs[t >> 6] = s; rw[t >> 6] = wsum; }
    __syncthreads();
    if (t == 0) {
        sentb[b] = rs[0] + rs[1];
        wordb[b] = rw[0] + rw[1];
    }
}

// ---------------- Pass 3: combine 32 per-b values -> scalar ----------------
__global__ __launch_bounds__(64)
void pass3(const float* __restrict__ sentb, const float* __restrict__ wordb,
           const int* __restrict__ lens, float* __restrict__ out)
{
    const int t = threadIdx.x;
    float s = 0.f, w = 0.f, L = 0.f;
    if (t < BATCH) { s = sentb[t]; w = wordb[t]; L = (float)lens[t]; }
    #pragma unroll
    for (int off = 32; off; off >>= 1) {
        s += __shfl_down(s, off);
        w += __shfl_down(w, off);
        L += __shfl_down(L, off);
    }
    if (t == 0) {
        const float word_loss = w / (L * (float)DDIM);
        const float sent_loss = s / ((float)DDIM * (float)BATCH);
        out[0] = word_loss + sent_loss;
    }
}

extern "C" void kernel_launch(void* const* d_in, const int* in_sizes, int n_in,
                              void* d_out, int out_size, void* d_ws, size_t ws_size,
                              hipStream_t stream) {
    const float* preds = (const float*)d_in[0];
    const float* targs = (const float*)d_in[1];
    const int*   lens  = (const int*)d_in[2];
    float* out = (float*)d_out;

    // Workspace (fp32, no init required — consumers only read slots producers wrote):
    //   colp_part [B*NCH*D] = 4 MB, colt_part = 4 MB, wpart [B*NCH], sentb[B], wordb[B]
    float* colp  = (float*)d_ws;
    float* colt  = colp + (size_t)BATCH * NCH * DDIM;
    float* wpart = colt + (size_t)BATCH * NCH * DDIM;
    float* sentb = wpart + BATCH * NCH;
    float* wordb = sentb + BATCH;

    dim3 grid1(BATCH, NCH);
    pass1<<<grid1, P1_THREADS, 0, stream>>>(preds, targs, lens,
                                            (float4*)colp, (float4*)colt, wpart);
    pass2<<<BATCH, 128, 0, stream>>>((const float4*)colp, (const float4*)colt,
                                     wpart, lens, sentb, wordb);
    pass3<<<1, 64, 0, stream>>>(sentb, wordb, lens, out);
}